// Round 3
// baseline (106.622 us; speedup 1.0000x reference)
//
#include <hip/hip_runtime.h>

#define NPARTS 16
#define NIN 4
#define NH 16
#define NO 3
#define NEG_SLOPE 0.01f
#define BN_EPS 1e-5f
#define NN 64
#define NF 512
#define NF4 (NF / 4)        // 128 float4 groups per row
#define BI_PER_BLOCK 4      // batches handled per block (staging amortization)

typedef float f4 __attribute__((ext_vector_type(4)));

// Branchless leaky ReLU: a>=0 -> a ; a<0 -> slope*a
__device__ __forceinline__ float leaky1(float a) {
    return fmaf(fminf(a, 0.0f), NEG_SLOPE - 1.0f, a);
}
__device__ __forceinline__ f4 leaky4(f4 a) {
    f4 r;
    r.x = leaky1(a.x); r.y = leaky1(a.y); r.z = leaky1(a.z); r.w = leaky1(a.w);
    return r;
}
// d += v * s (vector * broadcast-scalar)
__device__ __forceinline__ f4 fma4s(f4 v, float s, f4 d) {
    d.x = fmaf(v.x, s, d.x); d.y = fmaf(v.y, s, d.y);
    d.z = fmaf(v.z, s, d.z); d.w = fmaf(v.w, s, d.w);
    return d;
}

// One block per (bi-group, part p); 128 threads = one float4 group of fi each;
// each block loops over BI_PER_BLOCK batches (staging amortized, compiler can
// pipeline next batch's loads against current batch's MLP).
// x and out are streamed exactly once -> nontemporal (nt) loads/stores to
// avoid L2 pollution. Weights for part p staged in LDS (wave-uniform reads ->
// broadcast, no bank conflicts). BN folded into W2/shift.
__global__ __launch_bounds__(128)
void agg_joint_kernel(const float* __restrict__ x,
                      const int* __restrict__ parts,
                      const float* __restrict__ W1,
                      const float* __restrict__ b1,
                      const float* __restrict__ W2,
                      const float* __restrict__ b2,
                      const float* __restrict__ gamma,
                      const float* __restrict__ beta,
                      const float* __restrict__ mean,
                      const float* __restrict__ var,
                      float* __restrict__ out,
                      int batch)
{
    const int p   = blockIdx.x & (NPARTS - 1);
    const int big = blockIdx.x >> 4;           // batch group
    const int t   = threadIdx.x;               // fi4 index, 0..127

    __shared__ float s_w1[NIN * NH];   // [j][h]
    __shared__ float s_b1[NH];
    __shared__ float s_w2[NH * NO];    // [h][o], pre-scaled by BN scale
    __shared__ float s_shift[NO];      // (b2 - mean)*sc + beta
    __shared__ int   s_nidx[NIN];

    if (t < NIN * NH) s_w1[t] = W1[p * NIN * NH + t];
    if (t < NH)       s_b1[t] = b1[p * NH + t];
    if (t < NH * NO) {
        const int o = t % NO;
        const float sc = gamma[p * NO + o] * rsqrtf(var[p * NO + o] + BN_EPS);
        s_w2[t] = W2[p * NH * NO + t] * sc;
    }
    if (t < NO) {
        const float sc = gamma[p * NO + t] * rsqrtf(var[p * NO + t] + BN_EPS);
        s_shift[t] = (b2[p * NO + t] - mean[p * NO + t]) * sc + beta[p * NO + t];
    }
    if (t < NIN) s_nidx[t] = parts[p * NIN + t];
    __syncthreads();

#pragma unroll
    for (int u = 0; u < BI_PER_BLOCK; ++u) {
        const int bi = big * BI_PER_BLOCK + u;
        if (bi >= batch) break;

        // Gather 4 x rows' float4 for this (bi, fi4): 16 B/lane, coalesced,
        // nontemporal (streamed once).
        f4 xv[NIN];
#pragma unroll
        for (int j = 0; j < NIN; ++j) {
            const f4* xr = (const f4*)(x + ((size_t)bi * NN + s_nidx[j]) * NF);
            xv[j] = __builtin_nontemporal_load(xr + t);
        }

        // Output accumulators initialized with the folded BN shift.
        f4 acc[NO];
#pragma unroll
        for (int o = 0; o < NO; ++o) {
            const float s = s_shift[o];
            acc[o] = (f4){s, s, s, s};
        }

        // Hidden units one at a time, accumulated straight into acc.
#pragma unroll
        for (int k = 0; k < NH; ++k) {
            const float bk = s_b1[k];
            f4 h = (f4){bk, bk, bk, bk};
#pragma unroll
            for (int j = 0; j < NIN; ++j) h = fma4s(xv[j], s_w1[j * NH + k], h);
            h = leaky4(h);
#pragma unroll
            for (int o = 0; o < NO; ++o)
                acc[o] = fma4s(h, s_w2[k * NO + o], acc[o]);
        }

        // Final leaky ReLU + coalesced nontemporal float4 stores.
        f4* ob = (f4*)(out + ((size_t)bi * (NPARTS * NO) + p * NO) * NF);
#pragma unroll
        for (int o = 0; o < NO; ++o)
            __builtin_nontemporal_store(leaky4(acc[o]), ob + (size_t)o * NF4 + t);
    }
}

extern "C" void kernel_launch(void* const* d_in, const int* in_sizes, int n_in,
                              void* d_out, int out_size, void* d_ws, size_t ws_size,
                              hipStream_t stream) {
    const float* x     = (const float*)d_in[0];
    const int*   parts = (const int*)d_in[1];
    const float* W1    = (const float*)d_in[2];
    const float* b1    = (const float*)d_in[3];
    const float* W2    = (const float*)d_in[4];
    const float* b2    = (const float*)d_in[5];
    const float* gamma = (const float*)d_in[6];
    const float* beta  = (const float*)d_in[7];
    const float* mean  = (const float*)d_in[8];
    const float* var   = (const float*)d_in[9];
    float* out = (float*)d_out;

    const int batch = in_sizes[0] / (NN * NF);   // 256
    const int bgroups = (batch + BI_PER_BLOCK - 1) / BI_PER_BLOCK;
    dim3 grid(bgroups * NPARTS);                 // 1024 blocks
    dim3 block(128);
    agg_joint_kernel<<<grid, block, 0, stream>>>(
        x, parts, W1, b1, W2, b2, gamma, beta, mean, var, out, batch);
}

// Round 4
// 106.585 us; speedup vs baseline: 1.0003x; 1.0003x over previous
//
#include <hip/hip_runtime.h>

#define NPARTS 16
#define NIN 4
#define NH 16
#define NO 3
#define NEG_SLOPE 0.01f
#define BN_EPS 1e-5f
#define NN 64
#define NF 512
#define NF4 (NF / 4)   // 128 float4 groups per row

typedef float f4 __attribute__((ext_vector_type(4)));

// Branchless leaky ReLU: a>=0 -> a ; a<0 -> slope*a
__device__ __forceinline__ float leaky1(float a) {
    return fmaf(fminf(a, 0.0f), NEG_SLOPE - 1.0f, a);
}
__device__ __forceinline__ f4 leaky4(f4 a) {
    f4 r;
    r.x = leaky1(a.x); r.y = leaky1(a.y); r.z = leaky1(a.z); r.w = leaky1(a.w);
    return r;
}
// d += v * s (vector * broadcast-scalar)
__device__ __forceinline__ f4 fma4s(f4 v, float s, f4 d) {
    d.x = fmaf(v.x, s, d.x); d.y = fmaf(v.y, s, d.y);
    d.z = fmaf(v.z, s, d.z); d.w = fmaf(v.w, s, d.w);
    return d;
}

// One block per (batch bi, part p): grid 4096 x 128 threads = 8192 waves
// (~32 waves/CU -> full TLP; R3's 4-batch grouping cut this 4x and regressed).
// Each thread owns one float4 group of fi: all global traffic is 16 B/lane
// fully coalesced, nontemporal (x and out are streamed exactly once).
// Weights for part p staged in LDS (wave-uniform reads -> broadcast, no bank
// conflicts). BN folded: y = h.(W2*sc) + ((b2-mean)*sc + beta).
__global__ __launch_bounds__(128)
void agg_joint_kernel(const float* __restrict__ x,
                      const int* __restrict__ parts,
                      const float* __restrict__ W1,
                      const float* __restrict__ b1,
                      const float* __restrict__ W2,
                      const float* __restrict__ b2,
                      const float* __restrict__ gamma,
                      const float* __restrict__ beta,
                      const float* __restrict__ mean,
                      const float* __restrict__ var,
                      float* __restrict__ out)
{
    const int p  = blockIdx.x & (NPARTS - 1);
    const int bi = blockIdx.x >> 4;
    const int t  = threadIdx.x;   // fi4 index, 0..127

    __shared__ float s_w1[NIN * NH];   // [j][h]
    __shared__ float s_b1[NH];
    __shared__ float s_w2[NH * NO];    // [h][o], pre-scaled by BN scale
    __shared__ float s_shift[NO];      // (b2 - mean)*sc + beta
    __shared__ int   s_nidx[NIN];

    if (t < NIN * NH) s_w1[t] = W1[p * NIN * NH + t];
    if (t < NH)       s_b1[t] = b1[p * NH + t];
    if (t < NH * NO) {
        const int o = t % NO;
        const float sc = gamma[p * NO + o] * rsqrtf(var[p * NO + o] + BN_EPS);
        s_w2[t] = W2[p * NH * NO + t] * sc;
    }
    if (t < NO) {
        const float sc = gamma[p * NO + t] * rsqrtf(var[p * NO + t] + BN_EPS);
        s_shift[t] = (b2[p * NO + t] - mean[p * NO + t]) * sc + beta[p * NO + t];
    }
    if (t < NIN) s_nidx[t] = parts[p * NIN + t];
    __syncthreads();

    // Gather 4 x rows' float4 for this (bi, fi4): 16 B/lane, coalesced,
    // nontemporal (streamed once, no reuse).
    f4 xv[NIN];
#pragma unroll
    for (int j = 0; j < NIN; ++j) {
        const f4* xr = (const f4*)(x + ((size_t)bi * NN + s_nidx[j]) * NF);
        xv[j] = __builtin_nontemporal_load(xr + t);
    }

    // Output accumulators initialized with the folded BN shift.
    f4 acc[NO];
#pragma unroll
    for (int o = 0; o < NO; ++o) {
        const float s = s_shift[o];
        acc[o] = (f4){s, s, s, s};
    }

    // Hidden units one at a time, accumulated straight into acc.
#pragma unroll
    for (int k = 0; k < NH; ++k) {
        const float bk = s_b1[k];
        f4 h = (f4){bk, bk, bk, bk};
#pragma unroll
        for (int j = 0; j < NIN; ++j) h = fma4s(xv[j], s_w1[j * NH + k], h);
        h = leaky4(h);
#pragma unroll
        for (int o = 0; o < NO; ++o)
            acc[o] = fma4s(h, s_w2[k * NO + o], acc[o]);
    }

    // Final leaky ReLU + coalesced nontemporal float4 stores.
    f4* ob = (f4*)(out + ((size_t)bi * (NPARTS * NO) + p * NO) * NF);
#pragma unroll
    for (int o = 0; o < NO; ++o)
        __builtin_nontemporal_store(leaky4(acc[o]), ob + (size_t)o * NF4 + t);
}

extern "C" void kernel_launch(void* const* d_in, const int* in_sizes, int n_in,
                              void* d_out, int out_size, void* d_ws, size_t ws_size,
                              hipStream_t stream) {
    const float* x     = (const float*)d_in[0];
    const int*   parts = (const int*)d_in[1];
    const float* W1    = (const float*)d_in[2];
    const float* b1    = (const float*)d_in[3];
    const float* W2    = (const float*)d_in[4];
    const float* b2    = (const float*)d_in[5];
    const float* gamma = (const float*)d_in[6];
    const float* beta  = (const float*)d_in[7];
    const float* mean  = (const float*)d_in[8];
    const float* var   = (const float*)d_in[9];
    float* out = (float*)d_out;

    const int batch = in_sizes[0] / (NN * NF);   // 256
    dim3 grid(batch * NPARTS);                   // 4096 blocks
    dim3 block(128);
    agg_joint_kernel<<<grid, block, 0, stream>>>(
        x, parts, W1, b1, W2, b2, gamma, beta, mean, var, out);
}

// Round 5
// 100.639 us; speedup vs baseline: 1.0594x; 1.0591x over previous
//
#include <hip/hip_runtime.h>

#define NPARTS 16
#define NIN 4
#define NH 16
#define NO 3
#define NEG_SLOPE 0.01f
#define BN_EPS 1e-5f
#define NN 64
#define NF 512
#define NF4 (NF / 4)   // 128 float4 groups per row

typedef float f4 __attribute__((ext_vector_type(4)));

// Branchless leaky ReLU: a>=0 -> a ; a<0 -> slope*a
__device__ __forceinline__ float leaky1(float a) {
    return fmaf(fminf(a, 0.0f), NEG_SLOPE - 1.0f, a);
}
__device__ __forceinline__ f4 leaky4(f4 a) {
    f4 r;
    r.x = leaky1(a.x); r.y = leaky1(a.y); r.z = leaky1(a.z); r.w = leaky1(a.w);
    return r;
}
// d += v * s (vector * broadcast-scalar)
__device__ __forceinline__ f4 fma4s(f4 v, float s, f4 d) {
    d.x = fmaf(v.x, s, d.x); d.y = fmaf(v.y, s, d.y);
    d.z = fmaf(v.z, s, d.z); d.w = fmaf(v.w, s, d.w);
    return d;
}

// One block per (batch bi, part p): grid 4096 x 128 threads = 8192 waves
// (~32 waves/CU, full TLP). Each thread owns one float4 group of fi: all
// global traffic is 16 B/lane fully coalesced.
// NOTE: NO nontemporal hints — R3/R4 A/B showed nt costs +6 us here: the
// harness's pre-launch restore leaves x warm in the 256 MiB L3, and nt
// bypasses it (plus loses L2 store coalescing). Plain loads ride L3.
// Weights for part p staged in LDS (wave-uniform reads -> broadcast, no bank
// conflicts). BN folded: y = h.(W2*sc) + ((b2-mean)*sc + beta).
__global__ __launch_bounds__(128)
void agg_joint_kernel(const float* __restrict__ x,
                      const int* __restrict__ parts,
                      const float* __restrict__ W1,
                      const float* __restrict__ b1,
                      const float* __restrict__ W2,
                      const float* __restrict__ b2,
                      const float* __restrict__ gamma,
                      const float* __restrict__ beta,
                      const float* __restrict__ mean,
                      const float* __restrict__ var,
                      float* __restrict__ out)
{
    const int p  = blockIdx.x & (NPARTS - 1);
    const int bi = blockIdx.x >> 4;
    const int t  = threadIdx.x;   // fi4 index, 0..127

    __shared__ float s_w1[NIN * NH];   // [j][h]
    __shared__ float s_b1[NH];
    __shared__ float s_w2[NH * NO];    // [h][o], pre-scaled by BN scale
    __shared__ float s_shift[NO];      // (b2 - mean)*sc + beta
    __shared__ int   s_nidx[NIN];

    if (t < NIN * NH) s_w1[t] = W1[p * NIN * NH + t];
    if (t < NH)       s_b1[t] = b1[p * NH + t];
    if (t < NH * NO) {
        const int o = t % NO;
        const float sc = gamma[p * NO + o] * rsqrtf(var[p * NO + o] + BN_EPS);
        s_w2[t] = W2[p * NH * NO + t] * sc;
    }
    if (t < NO) {
        const float sc = gamma[p * NO + t] * rsqrtf(var[p * NO + t] + BN_EPS);
        s_shift[t] = (b2[p * NO + t] - mean[p * NO + t]) * sc + beta[p * NO + t];
    }
    if (t < NIN) s_nidx[t] = parts[p * NIN + t];
    __syncthreads();

    // Gather 4 x rows' float4 for this (bi, fi4): 16 B/lane, coalesced.
    f4 xv[NIN];
#pragma unroll
    for (int j = 0; j < NIN; ++j) {
        const f4* xr = (const f4*)(x + ((size_t)bi * NN + s_nidx[j]) * NF);
        xv[j] = xr[t];
    }

    // Output accumulators initialized with the folded BN shift.
    f4 acc[NO];
#pragma unroll
    for (int o = 0; o < NO; ++o) {
        const float s = s_shift[o];
        acc[o] = (f4){s, s, s, s};
    }

    // Hidden units one at a time, accumulated straight into acc.
#pragma unroll
    for (int k = 0; k < NH; ++k) {
        const float bk = s_b1[k];
        f4 h = (f4){bk, bk, bk, bk};
#pragma unroll
        for (int j = 0; j < NIN; ++j) h = fma4s(xv[j], s_w1[j * NH + k], h);
        h = leaky4(h);
#pragma unroll
        for (int o = 0; o < NO; ++o)
            acc[o] = fma4s(h, s_w2[k * NO + o], acc[o]);
    }

    // Final leaky ReLU + coalesced float4 stores.
    f4* ob = (f4*)(out + ((size_t)bi * (NPARTS * NO) + p * NO) * NF);
#pragma unroll
    for (int o = 0; o < NO; ++o)
        ob[(size_t)o * NF4 + t] = leaky4(acc[o]);
}

extern "C" void kernel_launch(void* const* d_in, const int* in_sizes, int n_in,
                              void* d_out, int out_size, void* d_ws, size_t ws_size,
                              hipStream_t stream) {
    const float* x     = (const float*)d_in[0];
    const int*   parts = (const int*)d_in[1];
    const float* W1    = (const float*)d_in[2];
    const float* b1    = (const float*)d_in[3];
    const float* W2    = (const float*)d_in[4];
    const float* b2    = (const float*)d_in[5];
    const float* gamma = (const float*)d_in[6];
    const float* beta  = (const float*)d_in[7];
    const float* mean  = (const float*)d_in[8];
    const float* var   = (const float*)d_in[9];
    float* out = (float*)d_out;

    const int batch = in_sizes[0] / (NN * NF);   // 256
    dim3 grid(batch * NPARTS);                   // 4096 blocks
    dim3 block(128);
    agg_joint_kernel<<<grid, block, 0, stream>>>(
        x, parts, W1, b1, W2, b2, gamma, beta, mean, var, out);
}